// Round 11
// baseline (433.184 us; speedup 1.0000x reference)
//
#include <hip/hip_runtime.h>
#include <math.h>

#define N_NODES 20000
#define N_EDGES 320000
#define N_GRAPH 64
#define IN_DIM  512
#define HID     256
#define F2      512   // HEADS*HID
#define EPS_BN  1e-5f
#define SLOPE   0.2f
#define SCAN_BLOCKS 79   // ceil(20000/256)
#define N_RT    157      // ceil(20000/128) row tiles
#define RT_PAD  20096    // 157*128: padded Fhi rows so tail A-loads are in-bounds

typedef unsigned short u16;
typedef __attribute__((ext_vector_type(8))) short bf16x8;
typedef __attribute__((ext_vector_type(4))) float floatx4;

// bf16 helpers: storage = upper 16 bits of fp32, round-to-nearest-even
__device__ __forceinline__ u16 bf_hi(float x) {
    unsigned int u = __float_as_uint(x);
    return (u16)((u + 0x7fffu + ((u >> 16) & 1u)) >> 16);
}
__device__ __forceinline__ float bf_val(u16 h) {
    return __uint_as_float((unsigned int)h << 16);
}
__device__ __forceinline__ void unpack2(unsigned int u, float& lo, float& hi) {
    lo = __uint_as_float(u << 16);
    hi = __uint_as_float(u & 0xffff0000u);
}
__device__ __forceinline__ float lr(float x) { return fmaxf(x, SLOPE * x); }

// ---------------- init: zero the ws regions that need it ----------------
__global__ void init_zero_kernel(int* counts, int* cursor, float* stats,
                                 float* h_gnum, float* gden, float* gate) {
    int i = blockIdx.x * blockDim.x + threadIdx.x;
    if (i < N_NODES) { counts[i] = 0; cursor[i] = 0; gate[i] = 0.f; }
    if (i < 1024) stats[i] = 0.f;
    if (i < N_GRAPH * HID) h_gnum[i] = 0.f;
    if (i < N_GRAPH) gden[i] = 0.f;
}

// ---------------- feat -> bf16 (row-major preserved, tail rows zeroed) --
__global__ __launch_bounds__(256) void split_feat_kernel(
    const float* __restrict__ X, u16* __restrict__ Hi, int total8, int pad8) {
    int i = blockIdx.x * 256 + threadIdx.x;
    if (i >= pad8) return;
    size_t base = (size_t)i * 8;
    if (i >= total8) {  // zero the pad rows (keeps MFMA tail clean)
        *(uint4*)(Hi + base) = make_uint4(0, 0, 0, 0);
        return;
    }
    float4 x0 = *(const float4*)(X + base);
    float4 x1 = *(const float4*)(X + base + 4);
    float xs[8] = {x0.x, x0.y, x0.z, x0.w, x1.x, x1.y, x1.z, x1.w};
    union { u16 s[8]; uint4 v; } h;
#pragma unroll
    for (int j = 0; j < 8; j++) h.s[j] = bf_hi(xs[j]);
    *(uint4*)(Hi + base) = h.v;
}

// --- transpose + split 4 weights: W[k][n] -> Wt[n][k] hi/lo -------------
// z=0..2: 512x512 (W_src,W_dst,W_skip); z=3: W_red 512x256.
__global__ __launch_bounds__(256) void split_wt_kernel(
    const float* __restrict__ Ws, const float* __restrict__ Wd,
    const float* __restrict__ Wk, const float* __restrict__ Wr,
    u16* __restrict__ Hi, u16* __restrict__ Lo) {
    __shared__ float t[32][33];
    int w = blockIdx.z;
    int ncols = (w == 3) ? 256 : 512;
    int n0 = blockIdx.y * 32;
    if (n0 >= ncols) return;
    const float* W = (w == 0) ? Ws : ((w == 1) ? Wd : ((w == 2) ? Wk : Wr));
    size_t obase = (size_t)w * 512 * 512;
    int k0 = blockIdx.x * 32;
    int tx = threadIdx.x, ty = threadIdx.y;  // 32 x 8
#pragma unroll
    for (int i = 0; i < 4; i++)
        t[ty * 4 + i][tx] = W[(size_t)(k0 + ty * 4 + i) * ncols + n0 + tx];
    __syncthreads();
#pragma unroll
    for (int i = 0; i < 4; i++) {
        float x = t[tx][ty * 4 + i];  // = W[k0+tx][n0+ty*4+i]
        u16 hh = bf_hi(x);
        size_t o = obase + (size_t)(n0 + ty * 4 + i) * 512 + k0 + tx;
        Hi[o] = hh;
        Lo[o] = bf_hi(x - bf_val(hh));
    }
}

// ------- fused triple MFMA GEMM (R10 structure, h1 now bf16 hi/lo) ------
__global__ __launch_bounds__(256) void gemm_mfma_triple(
    const u16* __restrict__ Fhi, const u16* __restrict__ Wthi,
    const float* __restrict__ b_src, const float* __restrict__ b_dst,
    const float* __restrict__ b_skip,
    u16* __restrict__ FS16, u16* __restrict__ FD16,
    u16* __restrict__ h1hi, u16* __restrict__ h1lo) {
    __shared__ u16 As[2][128 * 72];
    int b = blockIdx.x;
    int xcd = b & 7, slot = b >> 3;
    int rt = (slot / 12) * 8 + xcd;
    if (rt >= N_RT) return;
    int cw = slot % 12;
    int w_idx = cw >> 2;
    int col0 = (cw & 3) * 128;
    int row0 = rt * 128;
    int tid = threadIdx.x;
    int lane = tid & 63, wave = tid >> 6;
    int wm = (wave & 1) * 64, wn = (wave >> 1) * 64;
    int quad = lane >> 4, l16 = lane & 15;

    int sr = tid >> 1, sh = (tid & 1) * 32;
    const u16* gA = Fhi + (size_t)(row0 + sr) * 512 + sh;
    int sOff = sr * 72 + sh;

    const u16* Wb = Wthi + (size_t)w_idx * 512 * 512;
    const u16* bP[4];
#pragma unroll
    for (int nt = 0; nt < 4; nt++)
        bP[nt] = Wb + (size_t)(col0 + wn + nt * 16 + l16) * 512 + quad * 8;

    floatx4 acc[4][4];
#pragma unroll
    for (int i = 0; i < 4; i++)
#pragma unroll
        for (int j = 0; j < 4; j++) acc[i][j] = (floatx4){0.f, 0.f, 0.f, 0.f};

    union { uint4 u; bf16x8 v; } bcur[8], bnxt[8];
    {
        uint4 a0 = *(const uint4*)(gA + 0);
        uint4 a1 = *(const uint4*)(gA + 8);
        uint4 a2 = *(const uint4*)(gA + 16);
        uint4 a3 = *(const uint4*)(gA + 24);
#pragma unroll
        for (int nt = 0; nt < 4; nt++) {
            bcur[nt * 2 + 0].u = *(const uint4*)(bP[nt] + 0);
            bcur[nt * 2 + 1].u = *(const uint4*)(bP[nt] + 32);
        }
        *(uint4*)(&As[0][sOff + 0])  = a0;
        *(uint4*)(&As[0][sOff + 8])  = a1;
        *(uint4*)(&As[0][sOff + 16]) = a2;
        *(uint4*)(&As[0][sOff + 24]) = a3;
    }
    __syncthreads();

    for (int kk = 0; kk < 8; kk++) {
        uint4 na0, na1, na2, na3;
        bool more = kk < 7;
        if (more) {
            int k1 = (kk + 1) * 64;
            na0 = *(const uint4*)(gA + k1 + 0);
            na1 = *(const uint4*)(gA + k1 + 8);
            na2 = *(const uint4*)(gA + k1 + 16);
            na3 = *(const uint4*)(gA + k1 + 24);
#pragma unroll
            for (int nt = 0; nt < 4; nt++) {
                bnxt[nt * 2 + 0].u = *(const uint4*)(bP[nt] + k1 + 0);
                bnxt[nt * 2 + 1].u = *(const uint4*)(bP[nt] + k1 + 32);
            }
        }
        const u16* base = &As[kk & 1][0];
#pragma unroll
        for (int s = 0; s < 2; s++) {
#pragma unroll
            for (int mt = 0; mt < 4; mt++) {
                bf16x8 ah = *(const bf16x8*)&base[(wm + mt * 16 + l16) * 72 + s * 32 + quad * 8];
#pragma unroll
                for (int nt = 0; nt < 4; nt++)
                    acc[mt][nt] = __builtin_amdgcn_mfma_f32_16x16x32_bf16(ah, bcur[nt * 2 + s].v, acc[mt][nt], 0, 0, 0);
            }
        }
        if (more) {
            u16* d = &As[(kk + 1) & 1][sOff];
            *(uint4*)(d + 0)  = na0;
            *(uint4*)(d + 8)  = na1;
            *(uint4*)(d + 16) = na2;
            *(uint4*)(d + 24) = na3;
            __syncthreads();
#pragma unroll
            for (int i = 0; i < 8; i++) bcur[i] = bnxt[i];
        }
    }

    const float* bias = (w_idx == 0) ? b_src : ((w_idx == 1) ? b_dst : b_skip);
    float bv[4];
#pragma unroll
    for (int nt = 0; nt < 4; nt++) bv[nt] = bias[col0 + wn + nt * 16 + l16];
#pragma unroll
    for (int mt = 0; mt < 4; mt++) {
#pragma unroll
        for (int r = 0; r < 4; r++) {
            int m = row0 + wm + mt * 16 + quad * 4 + r;
            if (m < N_NODES) {
#pragma unroll
                for (int nt = 0; nt < 4; nt++) {
                    int n = col0 + wn + nt * 16 + l16;
                    float vv = acc[mt][nt][r] + bv[nt];
                    if (w_idx == 0)      FS16[(size_t)m * 512 + n] = bf_hi(vv);
                    else if (w_idx == 1) FD16[(size_t)m * 512 + n] = bf_hi(vv);
                    else {
                        u16 hh = bf_hi(vv);
                        h1hi[(size_t)m * 512 + n] = hh;
                        h1lo[(size_t)m * 512 + n] = bf_hi(vv - bf_val(hh));
                    }
                }
            }
        }
    }
}

// ---------------- CSR build ----------------
__global__ void hist_kernel(const int* __restrict__ dst, int* __restrict__ counts) {
    int e = blockIdx.x * blockDim.x + threadIdx.x;
    if (e < N_EDGES) atomicAdd(&counts[dst[e]], 1);
}

__global__ __launch_bounds__(256) void scan_local_kernel(
    const int* __restrict__ counts, int* __restrict__ row_ptr, int* __restrict__ bsum) {
    __shared__ int buf[256];
    int b = blockIdx.x, tid = threadIdx.x;
    int i = b * 256 + tid;
    buf[tid] = (i < N_NODES) ? counts[i] : 0;
    __syncthreads();
    for (int off = 1; off < 256; off <<= 1) {
        int t = (tid >= off) ? buf[tid - off] : 0;
        __syncthreads();
        buf[tid] += t;
        __syncthreads();
    }
    if (i < N_NODES) row_ptr[i + 1] = buf[tid];
    if (tid == 255) bsum[b] = buf[255];
}

__global__ __launch_bounds__(256) void scan_fixup_kernel(
    const int* __restrict__ bsum, int* __restrict__ row_ptr) {
    __shared__ int red[256];
    int b = blockIdx.x, tid = threadIdx.x;
    red[tid] = (tid < b) ? bsum[tid] : 0;
    __syncthreads();
    for (int off = 128; off > 0; off >>= 1) {
        if (tid < off) red[tid] += red[tid + off];
        __syncthreads();
    }
    int offset = red[0];
    int i = b * 256 + tid;
    if (i < N_NODES) row_ptr[i + 1] += offset;
    if (b == 0 && tid == 0) row_ptr[0] = 0;
}

__global__ void scatter_kernel(const int* __restrict__ src, const int* __restrict__ dst,
                               const int* __restrict__ row_ptr,
                               int* __restrict__ cursor, int* __restrict__ csr_src) {
    int e = blockIdx.x * blockDim.x + threadIdx.x;
    if (e < N_EDGES) {
        int d = dst[e];
        int pos = atomicAdd(&cursor[d], 1);
        csr_src[row_ptr[d] + pos] = src[e];
    }
}

// -------- fused edge phase (single pass; h1 skip RMW in bf16 hi/lo) -----
__global__ __launch_bounds__(256) void edge_fused_kernel(
    const u16* __restrict__ FS16, const u16* __restrict__ FD16,
    const float* __restrict__ attn, const int* __restrict__ csr_src,
    const int* __restrict__ row_ptr,
    u16* __restrict__ h1hi, u16* __restrict__ h1lo) {
    __shared__ float red[3 * 512];
    __shared__ float den[2];
    int n = blockIdx.x, tid = threadIdx.x;
    int lane = tid & 63, wave = tid >> 6;
    int beg = row_ptr[n], end = row_ptr[n + 1], deg = end - beg;
    if (tid < 2) den[tid] = 0.f;

    float fdv[8], aw[8];
    {
        uint4 q = *(const uint4*)(FD16 + (size_t)n * 512 + 8 * lane);
        unpack2(q.x, fdv[0], fdv[1]); unpack2(q.y, fdv[2], fdv[3]);
        unpack2(q.z, fdv[4], fdv[5]); unpack2(q.w, fdv[6], fdv[7]);
        float4 a0 = *(const float4*)(attn + 8 * lane);
        float4 a1 = *(const float4*)(attn + 8 * lane + 4);
        aw[0] = a0.x; aw[1] = a0.y; aw[2] = a0.z; aw[3] = a0.w;
        aw[4] = a1.x; aw[5] = a1.y; aw[6] = a1.z; aw[7] = a1.w;
    }
    __syncthreads();  // den init visible before LDS atomics

    float acc[8] = {0.f, 0.f, 0.f, 0.f, 0.f, 0.f, 0.f, 0.f};
    float dp = 0.f;
    for (int j = wave; j < deg; j += 4) {
        int s = csr_src[beg + j];
        uint4 q = *(const uint4*)(FS16 + (size_t)s * 512 + 8 * lane);
        float f[8];
        unpack2(q.x, f[0], f[1]); unpack2(q.y, f[2], f[3]);
        unpack2(q.z, f[4], f[5]); unpack2(q.w, f[6], f[7]);
        float p = 0.f;
#pragma unroll
        for (int k = 0; k < 8; k++) p += lr(f[k] + fdv[k]) * aw[k];
#pragma unroll
        for (int off = 16; off > 0; off >>= 1) p += __shfl_xor(p, off, 64);
        float ex = expf(p);  // shift-invariant: no max pass needed
#pragma unroll
        for (int k = 0; k < 8; k++) acc[k] += ex * f[k];
        if ((lane & 31) == 0) dp += ex;
    }
    if ((lane & 31) == 0) atomicAdd(&den[lane >> 5], dp);

    if (wave > 0) {
        float* r = &red[(wave - 1) * 512 + lane * 8];
        *(float4*)(r + 0) = *(float4*)&acc[0];
        *(float4*)(r + 4) = *(float4*)&acc[4];
    }
    __syncthreads();
    if (wave == 0) {
#pragma unroll
        for (int w = 0; w < 3; w++) {
            const float* r = &red[w * 512 + lane * 8];
#pragma unroll
            for (int k = 0; k < 8; k++) acc[k] += r[k];
        }
        float d = (lane < 32) ? den[0] : den[1];
        float inv = d > 0.f ? 1.f / d : 0.f;
        size_t base = (size_t)n * 512 + 8 * lane;
        union { u16 s[8]; uint4 v; } qh, ql;
        qh.v = *(const uint4*)(h1hi + base);
        ql.v = *(const uint4*)(h1lo + base);
#pragma unroll
        for (int k = 0; k < 8; k++) {
            float skip = bf_val(qh.s[k]) + bf_val(ql.s[k]);
            float x = acc[k] * inv;
            x = x > 0.f ? x : expm1f(x);
            float y = x + skip;
            u16 hh = bf_hi(y);
            qh.s[k] = hh;
            ql.s[k] = bf_hi(y - bf_val(hh));
        }
        *(uint4*)(h1hi + base) = qh.v;
        *(uint4*)(h1lo + base) = ql.v;
    }
}

// ---------------- BatchNorm stats (reads h1hi only: 20.5 MB) ------------
__global__ __launch_bounds__(256) void bn_stats_kernel(const u16* __restrict__ h1hi,
                                                       float* __restrict__ stats,
                                                       int rows_per_block) {
    int tid = threadIdx.x;
    int r0 = blockIdx.x * rows_per_block;
    int r1 = min(r0 + rows_per_block, N_NODES);
    float s0 = 0.f, q0 = 0.f, s1 = 0.f, q1 = 0.f;
    for (int r = r0; r < r1; r++) {
        float a = bf_val(h1hi[(size_t)r * F2 + tid]);
        float b = bf_val(h1hi[(size_t)r * F2 + 256 + tid]);
        s0 += a; q0 += a * a;
        s1 += b; q1 += b * b;
    }
    atomicAdd(&stats[tid], s0);
    atomicAdd(&stats[256 + tid], s1);
    atomicAdd(&stats[512 + tid], q0);
    atomicAdd(&stats[512 + 256 + tid], q1);
}

__global__ void bn_finalize_kernel(const float* __restrict__ stats,
                                   const float* __restrict__ gamma,
                                   const float* __restrict__ beta,
                                   float* __restrict__ bscale, float* __restrict__ bshift) {
    int c = threadIdx.x;  // 512 threads
    float mu = stats[c] / (float)N_NODES;
    float var = stats[512 + c] / (float)N_NODES - mu * mu;
    float sc = gamma[c] * rsqrtf(var + EPS_BN);
    bscale[c] = sc;
    bshift[c] = beta[c] - mu * sc;
}

// ---- fold BN into reducer weights: W'_nk = scale_k*W_nk (hi/lo split),
// ---- bias'_n = b_red_n + sum_k shift_k*W_nk. One block per n (256).
__global__ __launch_bounds__(256) void bn_fold_kernel(
    const u16* __restrict__ Whi3, const u16* __restrict__ Wlo3,
    const float* __restrict__ bscale, const float* __restrict__ bshift,
    const float* __restrict__ b_red,
    u16* __restrict__ Wphi, u16* __restrict__ Wplo, float* __restrict__ bias2) {
    __shared__ float red[256];
    int n = blockIdx.x, tid = threadIdx.x;
    float part = 0.f;
    for (int k = tid; k < 512; k += 256) {
        size_t o = (size_t)n * 512 + k;
        float w = bf_val(Whi3[o]) + bf_val(Wlo3[o]);
        part += bshift[k] * w;
        float wp = w * bscale[k];
        u16 hh = bf_hi(wp);
        Wphi[o] = hh;
        Wplo[o] = bf_hi(wp - bf_val(hh));
    }
    red[tid] = part; __syncthreads();
    for (int off = 128; off > 0; off >>= 1) {
        if (tid < off) red[tid] += red[tid + off];
        __syncthreads();
    }
    if (tid == 0) bias2[n] = b_red[n] + red[0];
}

// ------- reducer GEMM v2: lean 3-term (R4-structure, 48 MFMA/barrier) ---
// hr = h1(hi/lo) @ W'(hi/lo) + bias'. BN fully folded into W'/bias'.
// Gate fused into the epilogue: gate[m] += sum_n hr[m][n]*wg[n] (partials
// via quad-shfl reduce + atomicAdd; gate zero-initialized).
__global__ __launch_bounds__(256) void gemm_mfma_red(
    const u16* __restrict__ Ahi, const u16* __restrict__ Alo,
    const u16* __restrict__ Bhi, const u16* __restrict__ Blo,
    const float* __restrict__ bias2, const float* __restrict__ wg,
    float* __restrict__ hr, float* __restrict__ gate) {
    __shared__ u16 AsHi[128 * 40];
    __shared__ u16 AsLo[128 * 40];
    int tid = threadIdx.x;
    int row0 = blockIdx.x * 128;
    int col0 = blockIdx.y * 128;
    int lane = tid & 63, wave = tid >> 6;
    int wm = (wave & 1) * 64, wn = (wave >> 1) * 64;
    int quad = lane >> 4, l16 = lane & 15;

    int sr = tid >> 1, sh = (tid & 1) * 16;
    int grow = row0 + sr;
    bool ok = grow < N_NODES;
    u16* sH = &AsHi[sr * 40 + sh];
    u16* sL = &AsLo[sr * 40 + sh];

    const u16* bPh[4];
    const u16* bPl[4];
#pragma unroll
    for (int nt = 0; nt < 4; nt++) {
        size_t o = (size_t)(col0 + wn + nt * 16 + l16) * 512 + quad * 8;
        bPh[nt] = Bhi + o;
        bPl[nt] = Blo + o;
    }

    floatx4 acc[4][4];
#pragma unroll
    for (int i = 0; i < 4; i++)
#pragma unroll
        for (int j = 0; j < 4; j++) acc[i][j] = (floatx4){0.f, 0.f, 0.f, 0.f};

    for (int k0 = 0; k0 < 512; k0 += 32) {
        uint4 h0 = make_uint4(0, 0, 0, 0), h1v = h0, l0 = h0, l1 = h0;
        if (ok) {
            const u16* g = Ahi + (size_t)grow * 512 + k0 + sh;
            const u16* gl = Alo + (size_t)grow * 512 + k0 + sh;
            h0 = *(const uint4*)(g);
            h1v = *(const uint4*)(g + 8);
            l0 = *(const uint4*)(gl);
            l1 = *(const uint4*)(gl + 8);
        }
        union { uint4 u; bf16x8 v; } bh[4], bl[4];
#pragma unroll
        for (int nt = 0; nt < 4; nt++) {
            bh[nt].u = *(const uint4*)(bPh[nt] + k0);
            bl[nt].u = *(const uint4*)(bPl[nt] + k0);
        }
        __syncthreads();
        *(uint4*)(sH + 0) = h0;
        *(uint4*)(sH + 8) = h1v;
        *(uint4*)(sL + 0) = l0;
        *(uint4*)(sL + 8) = l1;
        __syncthreads();
#pragma unroll
        for (int mt = 0; mt < 4; mt++) {
            int me = (wm + mt * 16 + l16) * 40 + quad * 8;
            bf16x8 ah = *(const bf16x8*)&AsHi[me];
            bf16x8 al = *(const bf16x8*)&AsLo[me];
#pragma unroll
            for (int nt = 0; nt < 4; nt++) {
                acc[mt][nt] = __builtin_amdgcn_mfma_f32_16x16x32_bf16(ah, bh[nt].v, acc[mt][nt], 0, 0, 0);
                acc[mt][nt] = __builtin_amdgcn_mfma_f32_16x16x32_bf16(ah, bl[nt].v, acc[mt][nt], 0, 0, 0);
                acc[mt][nt] = __builtin_amdgcn_mfma_f32_16x16x32_bf16(al, bh[nt].v, acc[mt][nt], 0, 0, 0);
            }
        }
    }

    float bv[4], wgv[4];
#pragma unroll
    for (int nt = 0; nt < 4; nt++) {
        int n = col0 + wn + nt * 16 + l16;
        bv[nt] = bias2[n];
        wgv[nt] = wg[n];
    }
#pragma unroll
    for (int mt = 0; mt < 4; mt++) {
#pragma unroll
        for (int r = 0; r < 4; r++) {
            int m = row0 + wm + mt * 16 + quad * 4 + r;
            float vv[4], g = 0.f;
#pragma unroll
            for (int nt = 0; nt < 4; nt++) {
                vv[nt] = acc[mt][nt][r] + bv[nt];
                g += vv[nt] * wgv[nt];
            }
            // reduce over the 16 lanes of this quad (uniform execution)
#pragma unroll
            for (int s = 8; s > 0; s >>= 1) g += __shfl_xor(g, s, 64);
            if (m < N_NODES) {
#pragma unroll
                for (int nt = 0; nt < 4; nt++)
                    hr[(size_t)m * HID + col0 + wn + nt * 16 + l16] = vv[nt];
                if (l16 == 0) atomicAdd(&gate[m], g);
            }
        }
    }
}

// ---------------- per-graph attention pooling: 8 partial blocks / graph -
__device__ __forceinline__ int lower_bound_dev(const int* a, int n, int v) {
    int lo = 0, hi = n;
    while (lo < hi) {
        int mid = (lo + hi) >> 1;
        if (a[mid] < v) lo = mid + 1; else hi = mid;
    }
    return lo;
}

__global__ __launch_bounds__(256) void pool_partial_kernel(
    const float* __restrict__ hr, const float* __restrict__ gate,
    const int* __restrict__ gids, float* __restrict__ h_gnum,
    float* __restrict__ gden) {
    int b = blockIdx.x;
    int g = b >> 3, part = b & 7;
    int tid = threadIdx.x;
    int start = lower_bound_dev(gids, N_NODES, g);
    int end = lower_bound_dev(gids, N_NODES, g + 1);
    int span = end - start;
    int p_beg = start + (span * part) / 8;
    int p_end = start + (span * (part + 1)) / 8;
    if (p_beg >= p_end) return;
    __shared__ float wa[256];
    __shared__ float red[256];
    float acc = 0.f, denacc = 0.f;
    for (int cbeg = p_beg; cbeg < p_end; cbeg += 256) {
        int c = min(256, p_end - cbeg);
        float e = 0.f;
        if (tid < c) { e = expf(gate[cbeg + tid]); wa[tid] = e; }  // |gate| << 1: safe
        red[tid] = (tid < c) ? e : 0.f;
        __syncthreads();
        for (int off = 128; off > 0; off >>= 1) {
            if (tid < off) red[tid] += red[tid + off];
            __syncthreads();
        }
        denacc += red[0];
        for (int i = 0; i < c; i++) acc += wa[i] * hr[(size_t)(cbeg + i) * HID + tid];
        __syncthreads();
    }
    atomicAdd(&h_gnum[g * HID + tid], acc);
    if (tid == 0) atomicAdd(&gden[g], denacc);
}

// ---------------- classifier (finalizes pooling divide) -----------------
__global__ __launch_bounds__(128) void classifier_kernel(
    const float* __restrict__ h_gnum, const float* __restrict__ gden,
    const float* __restrict__ W1, const float* __restrict__ b1,
    const float* __restrict__ W2, const float* __restrict__ b2,
    float* __restrict__ out) {
    int g = blockIdx.x;
    int tid = threadIdx.x;  // 128
    __shared__ float hg[256];
    __shared__ float z1[128];
    float d = gden[g];
    float invd = d > 0.f ? 1.f / d : 0.f;
    hg[tid] = h_gnum[g * HID + tid] * invd;
    hg[tid + 128] = h_gnum[g * HID + tid + 128] * invd;
    __syncthreads();
    float a = b1[tid];
#pragma unroll 8
    for (int k = 0; k < 256; k++) a += hg[k] * W1[k * 128 + tid];
    z1[tid] = a > 0.f ? a : 0.f;
    __syncthreads();
    if (tid < 10) {
        float o = b2[tid];
#pragma unroll 8
        for (int j = 0; j < 128; j++) o += z1[j] * W2[j * 10 + tid];
        out[g * 10 + tid] = o;
    }
}

// ---------------- launcher ----------------
extern "C" void kernel_launch(void* const* d_in, const int* in_sizes, int n_in,
                              void* d_out, int out_size, void* d_ws, size_t ws_size,
                              hipStream_t stream) {
    const float* feat   = (const float*)d_in[0];
    const int*   src    = (const int*)d_in[1];
    const int*   dst    = (const int*)d_in[2];
    const int*   gids   = (const int*)d_in[3];
    const float* W_src  = (const float*)d_in[4];
    const float* b_src  = (const float*)d_in[5];
    const float* W_dst  = (const float*)d_in[6];
    const float* b_dst  = (const float*)d_in[7];
    const float* attn   = (const float*)d_in[8];
    const float* W_skip = (const float*)d_in[9];
    const float* b_skip = (const float*)d_in[10];
    const float* gamma  = (const float*)d_in[11];
    const float* beta   = (const float*)d_in[12];
    const float* W_red  = (const float*)d_in[13];
    const float* b_red  = (const float*)d_in[14];
    const float* w_gate = (const float*)d_in[15];
    const float* W1     = (const float*)d_in[17];
    const float* b1     = (const float*)d_in[18];
    const float* W2     = (const float*)d_in[19];
    const float* b2     = (const float*)d_in[20];
    float* out = (float*)d_out;

    char* p = (char*)d_ws;
    auto alloc = [&](size_t bytes) -> char* {
        char* r = p;
        p += (bytes + 255) & ~(size_t)255;
        return r;
    };
    u16*   FS16     = (u16*)alloc((size_t)N_NODES * F2 * 2);
    u16*   FD16     = (u16*)alloc((size_t)N_NODES * F2 * 2);
    u16*   h1hi     = (u16*)alloc((size_t)N_NODES * F2 * 2);
    u16*   h1lo     = (u16*)alloc((size_t)N_NODES * F2 * 2);
    float* gate     = (float*)alloc((size_t)N_NODES * 4);
    float* stats    = (float*)alloc(1024 * 4);
    float* bn_scale = (float*)alloc(512 * 4);
    float* bn_shift = (float*)alloc(512 * 4);
    float* bias2    = (float*)alloc(256 * 4);
    float* h_gnum   = (float*)alloc((size_t)N_GRAPH * HID * 4);
    float* gden     = (float*)alloc((size_t)N_GRAPH * 4);
    int* counts     = (int*)alloc((size_t)N_NODES * 4);
    int* row_ptr    = (int*)alloc((size_t)(N_NODES + 1) * 4);
    int* cursor     = (int*)alloc((size_t)N_NODES * 4);
    int* csr_src    = (int*)alloc((size_t)N_EDGES * 4);
    int* bsum       = (int*)alloc((size_t)SCAN_BLOCKS * 4);
    u16* Fhi        = (u16*)alloc((size_t)RT_PAD * IN_DIM * 2);  // padded; aliased as hr later
    u16* Wthi       = (u16*)alloc((size_t)4 * 512 * 512 * 2);
    u16* Wtlo       = (u16*)alloc((size_t)4 * 512 * 512 * 2);
    u16* Wphi       = (u16*)alloc((size_t)HID * 512 * 2);  // BN-folded reducer weights
    u16* Wplo       = (u16*)alloc((size_t)HID * 512 * 2);
    // hr (20.48 MB) aliases Fhi (20.58 MB): Fhi's last use (input GEMMs)
    // strictly precedes hr's first write (reducer GEMM).
    float* hr = (float*)Fhi;
    (void)ws_size; (void)in_sizes; (void)n_in; (void)out_size;

    const size_t WSZ = (size_t)512 * 512;

    // 1. init + input conversions
    init_zero_kernel<<<(N_NODES + 255) / 256, 256, 0, stream>>>(
        counts, cursor, stats, h_gnum, gden, gate);
    split_feat_kernel<<<(RT_PAD * IN_DIM / 8 + 255) / 256, 256, 0, stream>>>(
        feat, Fhi, N_NODES * IN_DIM / 8, RT_PAD * IN_DIM / 8);
    split_wt_kernel<<<dim3(16, 16, 4), dim3(32, 8), 0, stream>>>(
        W_src, W_dst, W_skip, W_red, Wthi, Wtlo);

    // 2. fused input GEMM triple (h1 skip written as bf16 hi/lo)
    gemm_mfma_triple<<<dim3(((N_RT + 7) / 8) * 8 * 12), 256, 0, stream>>>(
        Fhi, Wthi, b_src, b_dst, b_skip, FS16, FD16, h1hi, h1lo);

    // 3-5. CSR by dst
    hist_kernel<<<(N_EDGES + 255) / 256, 256, 0, stream>>>(dst, counts);
    scan_local_kernel<<<SCAN_BLOCKS, 256, 0, stream>>>(counts, row_ptr, bsum);
    scan_fixup_kernel<<<SCAN_BLOCKS, 256, 0, stream>>>(bsum, row_ptr);
    scatter_kernel<<<(N_EDGES + 255) / 256, 256, 0, stream>>>(src, dst, row_ptr, cursor, csr_src);

    // 6. fused edge phase (single pass; ELU+skip RMW on h1 hi/lo)
    edge_fused_kernel<<<N_NODES, 256, 0, stream>>>(
        FS16, FD16, attn, csr_src, row_ptr, h1hi, h1lo);

    // 7-9. BatchNorm stats -> scale/shift -> fold into reducer weights
    bn_stats_kernel<<<500, 256, 0, stream>>>(h1hi, stats, 40);
    bn_finalize_kernel<<<1, 512, 0, stream>>>(stats, gamma, beta, bn_scale, bn_shift);
    bn_fold_kernel<<<HID, 256, 0, stream>>>(
        Wthi + 3 * WSZ, Wtlo + 3 * WSZ, bn_scale, bn_shift, b_red, Wphi, Wplo, bias2);

    // 10. hr = h1 @ W' + bias'  (lean 3-term MFMA; gate fused in epilogue)
    dim3 g256((N_NODES + 127) / 128, 2);
    gemm_mfma_red<<<g256, 256, 0, stream>>>(
        h1hi, h1lo, Wphi, Wplo, bias2, w_gate, hr, gate);

    // 11. per-graph pooling (8 partial blocks per graph)
    pool_partial_kernel<<<N_GRAPH * 8, 256, 0, stream>>>(hr, gate, gids, h_gnum, gden);

    // 12. classifier (+ pooling divide)
    classifier_kernel<<<N_GRAPH, 128, 0, stream>>>(h_gnum, gden, W1, b1, W2, b2, out);
}

// Round 12
// 403.836 us; speedup vs baseline: 1.0727x; 1.0727x over previous
//
#include <hip/hip_runtime.h>
#include <math.h>

#define N_NODES 20000
#define N_EDGES 320000
#define N_GRAPH 64
#define IN_DIM  512
#define HID     256
#define F2      512   // HEADS*HID
#define EPS_BN  1e-5f
#define SLOPE   0.2f
#define SCAN_BLOCKS 79   // ceil(20000/256)
#define N_RT    157      // ceil(20000/128) row tiles
#define RT_PAD  20096    // 157*128: padded Fhi rows so tail A-loads are in-bounds

// prep mega-kernel block ranges (init + split_feat + split_wt fused)
#define SF_BLOCKS   5024   // RT_PAD*512/8/256
#define SW_BLOCKS   1024   // 16 x 16 x 4
#define INIT_BLOCKS 79
#define PREP_BLOCKS (SF_BLOCKS + SW_BLOCKS + INIT_BLOCKS)
// triple launch: 1920 GEMM blocks + 1250 hist blocks
#define TRIPLE_BLOCKS 1920
#define HIST_BLOCKS   1250

typedef unsigned short u16;
typedef __attribute__((ext_vector_type(8))) short bf16x8;
typedef __attribute__((ext_vector_type(4))) float floatx4;

// bf16 helpers: storage = upper 16 bits of fp32, round-to-nearest-even
__device__ __forceinline__ u16 bf_hi(float x) {
    unsigned int u = __float_as_uint(x);
    return (u16)((u + 0x7fffu + ((u >> 16) & 1u)) >> 16);
}
__device__ __forceinline__ float bf_val(u16 h) {
    return __uint_as_float((unsigned int)h << 16);
}
__device__ __forceinline__ void unpack2(unsigned int u, float& lo, float& hi) {
    lo = __uint_as_float(u << 16);
    hi = __uint_as_float(u & 0xffff0000u);
}
__device__ __forceinline__ float lr(float x) { return fmaxf(x, SLOPE * x); }

// ------- prep mega-kernel: split_feat + split_wt + init (independent) ---
__global__ __launch_bounds__(256) void prep_kernel(
    const float* __restrict__ feat, u16* __restrict__ Fhi,
    const float* __restrict__ Ws, const float* __restrict__ Wd,
    const float* __restrict__ Wk, const float* __restrict__ Wr,
    u16* __restrict__ Whi, u16* __restrict__ Wlo,
    int* __restrict__ counts, int* __restrict__ cursor,
    float* __restrict__ stats, float* __restrict__ h_gnum,
    float* __restrict__ gden, float* __restrict__ gate) {
    __shared__ float t[32][33];
    int b = blockIdx.x;
    int tid = threadIdx.x;
    if (b < SF_BLOCKS) {
        // ---- feat -> bf16 (pad rows zeroed) ----
        int i = b * 256 + tid;
        size_t base = (size_t)i * 8;
        if (i >= N_NODES * IN_DIM / 8) {
            *(uint4*)(Fhi + base) = make_uint4(0, 0, 0, 0);
            return;
        }
        float4 x0 = *(const float4*)(feat + base);
        float4 x1 = *(const float4*)(feat + base + 4);
        float xs[8] = {x0.x, x0.y, x0.z, x0.w, x1.x, x1.y, x1.z, x1.w};
        union { u16 s[8]; uint4 v; } h;
#pragma unroll
        for (int j = 0; j < 8; j++) h.s[j] = bf_hi(xs[j]);
        *(uint4*)(Fhi + base) = h.v;
    } else if (b < SF_BLOCKS + SW_BLOCKS) {
        // ---- transpose + split weights: W[k][n] -> Wt[n][k] hi/lo ----
        int bb = b - SF_BLOCKS;
        int kx = bb & 15, ny = (bb >> 4) & 15, w = bb >> 8;
        int ncols = (w == 3) ? 256 : 512;
        int n0 = ny * 32;
        if (n0 >= ncols) return;
        const float* W = (w == 0) ? Ws : ((w == 1) ? Wd : ((w == 2) ? Wk : Wr));
        size_t obase = (size_t)w * 512 * 512;
        int k0 = kx * 32;
        int tx = tid & 31, ty = tid >> 5;  // 32 x 8
#pragma unroll
        for (int i = 0; i < 4; i++)
            t[ty * 4 + i][tx] = W[(size_t)(k0 + ty * 4 + i) * ncols + n0 + tx];
        __syncthreads();
#pragma unroll
        for (int i = 0; i < 4; i++) {
            float x = t[tx][ty * 4 + i];  // = W[k0+tx][n0+ty*4+i]
            u16 hh = bf_hi(x);
            size_t o = obase + (size_t)(n0 + ty * 4 + i) * 512 + k0 + tx;
            Whi[o] = hh;
            Wlo[o] = bf_hi(x - bf_val(hh));
        }
    } else {
        // ---- init: zero counters/accumulators ----
        int i = (b - SF_BLOCKS - SW_BLOCKS) * 256 + tid;
        if (i < N_NODES) { counts[i] = 0; cursor[i] = 0; gate[i] = 0.f; }
        if (i < 1024) stats[i] = 0.f;
        if (i < N_GRAPH * HID) h_gnum[i] = 0.f;
        if (i < N_GRAPH) gden[i] = 0.f;
    }
}

// ------- fused triple MFMA GEMM, TRANSPOSED-C epilogue ------------------
// mfma(W-frag, feat-frag) => D reg r = col n (4 consecutive), lane = row m
// -> packed 8B stores (4x fewer store instructions; the measured plateau).
// hist (counts histogram) rides along as blocks >= TRIPLE_BLOCKS.
__global__ __launch_bounds__(256) void gemm_mfma_triple(
    const u16* __restrict__ Fhi, const u16* __restrict__ Wthi,
    const float* __restrict__ b_src, const float* __restrict__ b_dst,
    const float* __restrict__ b_skip,
    u16* __restrict__ FS16, u16* __restrict__ FD16,
    u16* __restrict__ h1hi, u16* __restrict__ h1lo,
    const int* __restrict__ dst, int* __restrict__ counts) {
    __shared__ u16 As[2][128 * 72];
    int b = blockIdx.x;
    if (b >= TRIPLE_BLOCKS) {  // hist branch
        int e = (b - TRIPLE_BLOCKS) * 256 + threadIdx.x;
        if (e < N_EDGES) atomicAdd(&counts[dst[e]], 1);
        return;
    }
    int xcd = b & 7, slot = b >> 3;
    int rt = (slot / 12) * 8 + xcd;
    if (rt >= N_RT) return;
    int cw = slot % 12;
    int w_idx = cw >> 2;
    int col0 = (cw & 3) * 128;
    int row0 = rt * 128;
    int tid = threadIdx.x;
    int lane = tid & 63, wave = tid >> 6;
    int wm = (wave & 1) * 64, wn = (wave >> 1) * 64;
    int quad = lane >> 4, l16 = lane & 15;

    int sr = tid >> 1, sh = (tid & 1) * 32;
    const u16* gA = Fhi + (size_t)(row0 + sr) * 512 + sh;
    int sOff = sr * 72 + sh;

    const u16* Wb = Wthi + (size_t)w_idx * 512 * 512;
    const u16* bP[4];
#pragma unroll
    for (int nt = 0; nt < 4; nt++)
        bP[nt] = Wb + (size_t)(col0 + wn + nt * 16 + l16) * 512 + quad * 8;

    floatx4 acc[4][4];
#pragma unroll
    for (int i = 0; i < 4; i++)
#pragma unroll
        for (int j = 0; j < 4; j++) acc[i][j] = (floatx4){0.f, 0.f, 0.f, 0.f};

    union { uint4 u; bf16x8 v; } bcur[8], bnxt[8];
    {
        uint4 a0 = *(const uint4*)(gA + 0);
        uint4 a1 = *(const uint4*)(gA + 8);
        uint4 a2 = *(const uint4*)(gA + 16);
        uint4 a3 = *(const uint4*)(gA + 24);
#pragma unroll
        for (int nt = 0; nt < 4; nt++) {
            bcur[nt * 2 + 0].u = *(const uint4*)(bP[nt] + 0);
            bcur[nt * 2 + 1].u = *(const uint4*)(bP[nt] + 32);
        }
        *(uint4*)(&As[0][sOff + 0])  = a0;
        *(uint4*)(&As[0][sOff + 8])  = a1;
        *(uint4*)(&As[0][sOff + 16]) = a2;
        *(uint4*)(&As[0][sOff + 24]) = a3;
    }
    __syncthreads();

    for (int kk = 0; kk < 8; kk++) {
        uint4 na0, na1, na2, na3;
        bool more = kk < 7;
        if (more) {
            int k1 = (kk + 1) * 64;
            na0 = *(const uint4*)(gA + k1 + 0);
            na1 = *(const uint4*)(gA + k1 + 8);
            na2 = *(const uint4*)(gA + k1 + 16);
            na3 = *(const uint4*)(gA + k1 + 24);
#pragma unroll
            for (int nt = 0; nt < 4; nt++) {
                bnxt[nt * 2 + 0].u = *(const uint4*)(bP[nt] + k1 + 0);
                bnxt[nt * 2 + 1].u = *(const uint4*)(bP[nt] + k1 + 32);
            }
        }
        const u16* base = &As[kk & 1][0];
#pragma unroll
        for (int s = 0; s < 2; s++) {
#pragma unroll
            for (int mt = 0; mt < 4; mt++) {
                bf16x8 ah = *(const bf16x8*)&base[(wm + mt * 16 + l16) * 72 + s * 32 + quad * 8];
#pragma unroll
                for (int nt = 0; nt < 4; nt++)
                    acc[mt][nt] = __builtin_amdgcn_mfma_f32_16x16x32_bf16(
                        bcur[nt * 2 + s].v, ah, acc[mt][nt], 0, 0, 0);  // SWAPPED
            }
        }
        if (more) {
            u16* d = &As[(kk + 1) & 1][sOff];
            *(uint4*)(d + 0)  = na0;
            *(uint4*)(d + 8)  = na1;
            *(uint4*)(d + 16) = na2;
            *(uint4*)(d + 24) = na3;
            __syncthreads();
#pragma unroll
            for (int i = 0; i < 8; i++) bcur[i] = bnxt[i];
        }
    }

    // transposed-C epilogue: lane l16 = row m, reg r = col nb+r (consecutive)
    const float* bias = (w_idx == 0) ? b_src : ((w_idx == 1) ? b_dst : b_skip);
    float4 b4[4];
#pragma unroll
    for (int wt = 0; wt < 4; wt++)
        b4[wt] = *(const float4*)(bias + col0 + wn + wt * 16 + quad * 4);
#pragma unroll
    for (int ft = 0; ft < 4; ft++) {
        int m = row0 + wm + ft * 16 + l16;
        if (m >= N_NODES) continue;
        size_t rb = (size_t)m * 512;
#pragma unroll
        for (int wt = 0; wt < 4; wt++) {
            int nb = col0 + wn + wt * 16 + quad * 4;
            float v0 = acc[ft][wt][0] + b4[wt].x;
            float v1 = acc[ft][wt][1] + b4[wt].y;
            float v2 = acc[ft][wt][2] + b4[wt].z;
            float v3 = acc[ft][wt][3] + b4[wt].w;
            u16 h0 = bf_hi(v0), h1_ = bf_hi(v1), h2 = bf_hi(v2), h3 = bf_hi(v3);
            uint2 wv;
            wv.x = (unsigned)h0 | ((unsigned)h1_ << 16);
            wv.y = (unsigned)h2 | ((unsigned)h3 << 16);
            if (w_idx == 0)      *(uint2*)(FS16 + rb + nb) = wv;
            else if (w_idx == 1) *(uint2*)(FD16 + rb + nb) = wv;
            else {
                *(uint2*)(h1hi + rb + nb) = wv;
                uint2 lv;
                lv.x = (unsigned)bf_hi(v0 - bf_val(h0)) | ((unsigned)bf_hi(v1 - bf_val(h1_)) << 16);
                lv.y = (unsigned)bf_hi(v2 - bf_val(h2)) | ((unsigned)bf_hi(v3 - bf_val(h3)) << 16);
                *(uint2*)(h1lo + rb + nb) = lv;
            }
        }
    }
}

// ---------------- CSR scan + scatter ----------------
__global__ __launch_bounds__(256) void scan_local_kernel(
    const int* __restrict__ counts, int* __restrict__ row_ptr, int* __restrict__ bsum) {
    __shared__ int buf[256];
    int b = blockIdx.x, tid = threadIdx.x;
    int i = b * 256 + tid;
    buf[tid] = (i < N_NODES) ? counts[i] : 0;
    __syncthreads();
    for (int off = 1; off < 256; off <<= 1) {
        int t = (tid >= off) ? buf[tid - off] : 0;
        __syncthreads();
        buf[tid] += t;
        __syncthreads();
    }
    if (i < N_NODES) row_ptr[i + 1] = buf[tid];
    if (tid == 255) bsum[b] = buf[255];
}

__global__ __launch_bounds__(256) void scan_fixup_kernel(
    const int* __restrict__ bsum, int* __restrict__ row_ptr) {
    __shared__ int red[256];
    int b = blockIdx.x, tid = threadIdx.x;
    red[tid] = (tid < b) ? bsum[tid] : 0;
    __syncthreads();
    for (int off = 128; off > 0; off >>= 1) {
        if (tid < off) red[tid] += red[tid + off];
        __syncthreads();
    }
    int offset = red[0];
    int i = b * 256 + tid;
    if (i < N_NODES) row_ptr[i + 1] += offset;
    if (b == 0 && tid == 0) row_ptr[0] = 0;
}

__global__ void scatter_kernel(const int* __restrict__ src, const int* __restrict__ dst,
                               const int* __restrict__ row_ptr,
                               int* __restrict__ cursor, int* __restrict__ csr_src) {
    int e = blockIdx.x * blockDim.x + threadIdx.x;
    if (e < N_EDGES) {
        int d = dst[e];
        int pos = atomicAdd(&cursor[d], 1);
        csr_src[row_ptr[d] + pos] = src[e];
    }
}

// -------- fused edge phase (single pass; h1 skip RMW in bf16 hi/lo) -----
__global__ __launch_bounds__(256) void edge_fused_kernel(
    const u16* __restrict__ FS16, const u16* __restrict__ FD16,
    const float* __restrict__ attn, const int* __restrict__ csr_src,
    const int* __restrict__ row_ptr,
    u16* __restrict__ h1hi, u16* __restrict__ h1lo) {
    __shared__ float red[3 * 512];
    __shared__ float den[2];
    int n = blockIdx.x, tid = threadIdx.x;
    int lane = tid & 63, wave = tid >> 6;
    int beg = row_ptr[n], end = row_ptr[n + 1], deg = end - beg;
    if (tid < 2) den[tid] = 0.f;

    float fdv[8], aw[8];
    {
        uint4 q = *(const uint4*)(FD16 + (size_t)n * 512 + 8 * lane);
        unpack2(q.x, fdv[0], fdv[1]); unpack2(q.y, fdv[2], fdv[3]);
        unpack2(q.z, fdv[4], fdv[5]); unpack2(q.w, fdv[6], fdv[7]);
        float4 a0 = *(const float4*)(attn + 8 * lane);
        float4 a1 = *(const float4*)(attn + 8 * lane + 4);
        aw[0] = a0.x; aw[1] = a0.y; aw[2] = a0.z; aw[3] = a0.w;
        aw[4] = a1.x; aw[5] = a1.y; aw[6] = a1.z; aw[7] = a1.w;
    }
    __syncthreads();  // den init visible before LDS atomics

    float acc[8] = {0.f, 0.f, 0.f, 0.f, 0.f, 0.f, 0.f, 0.f};
    float dp = 0.f;
    for (int j = wave; j < deg; j += 4) {
        int s = csr_src[beg + j];
        uint4 q = *(const uint4*)(FS16 + (size_t)s * 512 + 8 * lane);
        float f[8];
        unpack2(q.x, f[0], f[1]); unpack2(q.y, f[2], f[3]);
        unpack2(q.z, f[4], f[5]); unpack2(q.w, f[6], f[7]);
        float p = 0.f;
#pragma unroll
        for (int k = 0; k < 8; k++) p += lr(f[k] + fdv[k]) * aw[k];
#pragma unroll
        for (int off = 16; off > 0; off >>= 1) p += __shfl_xor(p, off, 64);
        float ex = expf(p);  // shift-invariant: no max pass needed
#pragma unroll
        for (int k = 0; k < 8; k++) acc[k] += ex * f[k];
        if ((lane & 31) == 0) dp += ex;
    }
    if ((lane & 31) == 0) atomicAdd(&den[lane >> 5], dp);

    if (wave > 0) {
        float* r = &red[(wave - 1) * 512 + lane * 8];
        *(float4*)(r + 0) = *(float4*)&acc[0];
        *(float4*)(r + 4) = *(float4*)&acc[4];
    }
    __syncthreads();
    if (wave == 0) {
#pragma unroll
        for (int w = 0; w < 3; w++) {
            const float* r = &red[w * 512 + lane * 8];
#pragma unroll
            for (int k = 0; k < 8; k++) acc[k] += r[k];
        }
        float d = (lane < 32) ? den[0] : den[1];
        float inv = d > 0.f ? 1.f / d : 0.f;
        size_t base = (size_t)n * 512 + 8 * lane;
        union { u16 s[8]; uint4 v; } qh, ql;
        qh.v = *(const uint4*)(h1hi + base);
        ql.v = *(const uint4*)(h1lo + base);
#pragma unroll
        for (int k = 0; k < 8; k++) {
            float skip = bf_val(qh.s[k]) + bf_val(ql.s[k]);
            float x = acc[k] * inv;
            x = x > 0.f ? x : expm1f(x);
            float y = x + skip;
            u16 hh = bf_hi(y);
            qh.s[k] = hh;
            ql.s[k] = bf_hi(y - bf_val(hh));
        }
        *(uint4*)(h1hi + base) = qh.v;
        *(uint4*)(h1lo + base) = ql.v;
    }
}

// ---------------- BatchNorm stats (reads h1hi only: 20.5 MB) ------------
__global__ __launch_bounds__(256) void bn_stats_kernel(const u16* __restrict__ h1hi,
                                                       float* __restrict__ stats,
                                                       int rows_per_block) {
    int tid = threadIdx.x;
    int r0 = blockIdx.x * rows_per_block;
    int r1 = min(r0 + rows_per_block, N_NODES);
    float s0 = 0.f, q0 = 0.f, s1 = 0.f, q1 = 0.f;
    for (int r = r0; r < r1; r++) {
        float a = bf_val(h1hi[(size_t)r * F2 + tid]);
        float b = bf_val(h1hi[(size_t)r * F2 + 256 + tid]);
        s0 += a; q0 += a * a;
        s1 += b; q1 += b * b;
    }
    atomicAdd(&stats[tid], s0);
    atomicAdd(&stats[256 + tid], s1);
    atomicAdd(&stats[512 + tid], q0);
    atomicAdd(&stats[512 + 256 + tid], q1);
}

// ---- BN finalize + fold into reducer weights, one kernel ---------------
// Each of the 256 blocks recomputes scale/shift for all 512 channels in
// LDS (trivial), then W'_nk = scale_k*W_nk (hi/lo), bias'_n = b_red_n +
// sum_k shift_k*W_nk.
__global__ __launch_bounds__(256) void bn_fold_kernel(
    const float* __restrict__ stats, const float* __restrict__ gamma,
    const float* __restrict__ beta,
    const u16* __restrict__ Whi3, const u16* __restrict__ Wlo3,
    const float* __restrict__ b_red,
    u16* __restrict__ Wphi, u16* __restrict__ Wplo, float* __restrict__ bias2) {
    __shared__ float sScale[512], sShift[512];
    __shared__ float red[256];
    int n = blockIdx.x, tid = threadIdx.x;
    for (int c = tid; c < 512; c += 256) {
        float mu = stats[c] / (float)N_NODES;
        float var = stats[512 + c] / (float)N_NODES - mu * mu;
        float sc = gamma[c] * rsqrtf(var + EPS_BN);
        sScale[c] = sc;
        sShift[c] = beta[c] - mu * sc;
    }
    __syncthreads();
    float part = 0.f;
    for (int k = tid; k < 512; k += 256) {
        size_t o = (size_t)n * 512 + k;
        float w = bf_val(Whi3[o]) + bf_val(Wlo3[o]);
        part += sShift[k] * w;
        float wp = w * sScale[k];
        u16 hh = bf_hi(wp);
        Wphi[o] = hh;
        Wplo[o] = bf_hi(wp - bf_val(hh));
    }
    red[tid] = part; __syncthreads();
    for (int off = 128; off > 0; off >>= 1) {
        if (tid < off) red[tid] += red[tid + off];
        __syncthreads();
    }
    if (tid == 0) bias2[n] = b_red[n] + red[0];
}

// ------- reducer GEMM: lean 3-term, TRANSPOSED-C (float4 stores) --------
// hr = h1(hi/lo) @ W'(hi/lo) + bias'; gate fused (quad-reduce + atomic).
__global__ __launch_bounds__(256) void gemm_mfma_red(
    const u16* __restrict__ Ahi, const u16* __restrict__ Alo,
    const u16* __restrict__ Bhi, const u16* __restrict__ Blo,
    const float* __restrict__ bias2, const float* __restrict__ wg,
    float* __restrict__ hr, float* __restrict__ gate) {
    __shared__ u16 AsHi[128 * 40];
    __shared__ u16 AsLo[128 * 40];
    int tid = threadIdx.x;
    int row0 = blockIdx.x * 128;
    int col0 = blockIdx.y * 128;
    int lane = tid & 63, wave = tid >> 6;
    int wm = (wave & 1) * 64, wn = (wave >> 1) * 64;
    int quad = lane >> 4, l16 = lane & 15;

    int sr = tid >> 1, sh = (tid & 1) * 16;
    int grow = row0 + sr;
    bool ok = grow < N_NODES;
    u16* sH = &AsHi[sr * 40 + sh];
    u16* sL = &AsLo[sr * 40 + sh];

    const u16* bPh[4];
    const u16* bPl[4];
#pragma unroll
    for (int nt = 0; nt < 4; nt++) {
        size_t o = (size_t)(col0 + wn + nt * 16 + l16) * 512 + quad * 8;
        bPh[nt] = Bhi + o;
        bPl[nt] = Blo + o;
    }

    floatx4 acc[4][4];
#pragma unroll
    for (int i = 0; i < 4; i++)
#pragma unroll
        for (int j = 0; j < 4; j++) acc[i][j] = (floatx4){0.f, 0.f, 0.f, 0.f};

    for (int k0 = 0; k0 < 512; k0 += 32) {
        uint4 h0 = make_uint4(0, 0, 0, 0), h1v = h0, l0 = h0, l1 = h0;
        if (ok) {
            const u16* g = Ahi + (size_t)grow * 512 + k0 + sh;
            const u16* gl = Alo + (size_t)grow * 512 + k0 + sh;
            h0 = *(const uint4*)(g);
            h1v = *(const uint4*)(g + 8);
            l0 = *(const uint4*)(gl);
            l1 = *(const uint4*)(gl + 8);
        }
        union { uint4 u; bf16x8 v; } bh[4], bl[4];
#pragma unroll
        for (int nt = 0; nt < 4; nt++) {
            bh[nt].u = *(const uint4*)(bPh[nt] + k0);
            bl[nt].u = *(const uint4*)(bPl[nt] + k0);
        }
        __syncthreads();
        *(uint4*)(sH + 0) = h0;
        *(uint4*)(sH + 8) = h1v;
        *(uint4*)(sL + 0) = l0;
        *(uint4*)(sL + 8) = l1;
        __syncthreads();
#pragma unroll
        for (int mt = 0; mt < 4; mt++) {
            int me = (wm + mt * 16 + l16) * 40 + quad * 8;
            bf16x8 ah = *(const bf16x8*)&AsHi[me];
            bf16x8 al = *(const bf16x8*)&AsLo[me];
#pragma unroll
            for (int nt = 0; nt < 4; nt++) {
                acc[mt][nt] = __builtin_amdgcn_mfma_f32_16x16x32_bf16(bh[nt].v, ah, acc[mt][nt], 0, 0, 0);
                acc[mt][nt] = __builtin_amdgcn_mfma_f32_16x16x32_bf16(bl[nt].v, ah, acc[mt][nt], 0, 0, 0);
                acc[mt][nt] = __builtin_amdgcn_mfma_f32_16x16x32_bf16(bh[nt].v, al, acc[mt][nt], 0, 0, 0);
            }
        }
    }

    // transposed-C epilogue: lane l16 = row m; reg r = col (consecutive)
    float4 b4[4], w4[4];
#pragma unroll
    for (int wt = 0; wt < 4; wt++) {
        int nb = col0 + wn + wt * 16 + quad * 4;
        b4[wt] = *(const float4*)(bias2 + nb);
        w4[wt] = *(const float4*)(wg + nb);
    }
#pragma unroll
    for (int ft = 0; ft < 4; ft++) {
        int m = row0 + wm + ft * 16 + l16;
        bool ok2 = m < N_NODES;
        float g = 0.f;
#pragma unroll
        for (int wt = 0; wt < 4; wt++) {
            float4 v;
            v.x = acc[ft][wt][0] + b4[wt].x;
            v.y = acc[ft][wt][1] + b4[wt].y;
            v.z = acc[ft][wt][2] + b4[wt].z;
            v.w = acc[ft][wt][3] + b4[wt].w;
            g += v.x * w4[wt].x + v.y * w4[wt].y + v.z * w4[wt].z + v.w * w4[wt].w;
            if (ok2) *(float4*)(hr + (size_t)m * HID + col0 + wn + wt * 16 + quad * 4) = v;
        }
        g += __shfl_xor(g, 16, 64);
        g += __shfl_xor(g, 32, 64);
        if (ok2 && lane < 16) atomicAdd(&gate[m], g);
    }
}

// ---------------- per-graph attention pooling: 8 partial blocks / graph -
__device__ __forceinline__ int lower_bound_dev(const int* a, int n, int v) {
    int lo = 0, hi = n;
    while (lo < hi) {
        int mid = (lo + hi) >> 1;
        if (a[mid] < v) lo = mid + 1; else hi = mid;
    }
    return lo;
}

__global__ __launch_bounds__(256) void pool_partial_kernel(
    const float* __restrict__ hr, const float* __restrict__ gate,
    const int* __restrict__ gids, float* __restrict__ h_gnum,
    float* __restrict__ gden) {
    int b = blockIdx.x;
    int g = b >> 3, part = b & 7;
    int tid = threadIdx.x;
    int start = lower_bound_dev(gids, N_NODES, g);
    int end = lower_bound_dev(gids, N_NODES, g + 1);
    int span = end - start;
    int p_beg = start + (span * part) / 8;
    int p_end = start + (span * (part + 1)) / 8;
    if (p_beg >= p_end) return;
    __shared__ float wa[256];
    __shared__ float red[256];
    float acc = 0.f, denacc = 0.f;
    for (int cbeg = p_beg; cbeg < p_end; cbeg += 256) {
        int c = min(256, p_end - cbeg);
        float e = 0.f;
        if (tid < c) { e = expf(gate[cbeg + tid]); wa[tid] = e; }  // |gate| << 1: safe
        red[tid] = (tid < c) ? e : 0.f;
        __syncthreads();
        for (int off = 128; off > 0; off >>= 1) {
            if (tid < off) red[tid] += red[tid + off];
            __syncthreads();
        }
        denacc += red[0];
        for (int i = 0; i < c; i++) acc += wa[i] * hr[(size_t)(cbeg + i) * HID + tid];
        __syncthreads();
    }
    atomicAdd(&h_gnum[g * HID + tid], acc);
    if (tid == 0) atomicAdd(&gden[g], denacc);
}

// ---------------- classifier (finalizes pooling divide) -----------------
__global__ __launch_bounds__(128) void classifier_kernel(
    const float* __restrict__ h_gnum, const float* __restrict__ gden,
    const float* __restrict__ W1, const float* __restrict__ b1,
    const float* __restrict__ W2, const float* __restrict__ b2,
    float* __restrict__ out) {
    int g = blockIdx.x;
    int tid = threadIdx.x;  // 128
    __shared__ float hg[256];
    __shared__ float z1[128];
    float d = gden[g];
    float invd = d > 0.f ? 1.f / d : 0.f;
    hg[tid] = h_gnum[g * HID + tid] * invd;
    hg[tid + 128] = h_gnum[g * HID + tid + 128] * invd;
    __syncthreads();
    float a = b1[tid];
#pragma unroll 8
    for (int k = 0; k < 256; k++) a += hg[k] * W1[k * 128 + tid];
    z1[tid] = a > 0.f ? a : 0.f;
    __syncthreads();
    if (tid < 10) {
        float o = b2[tid];
#pragma unroll 8
        for (int j = 0; j < 128; j++) o += z1[j] * W2[j * 10 + tid];
        out[g * 10 + tid] = o;
    }
}

// ---------------- launcher ----------------
extern "C" void kernel_launch(void* const* d_in, const int* in_sizes, int n_in,
                              void* d_out, int out_size, void* d_ws, size_t ws_size,
                              hipStream_t stream) {
    const float* feat   = (const float*)d_in[0];
    const int*   src    = (const int*)d_in[1];
    const int*   dst    = (const int*)d_in[2];
    const int*   gids   = (const int*)d_in[3];
    const float* W_src  = (const float*)d_in[4];
    const float* b_src  = (const float*)d_in[5];
    const float* W_dst  = (const float*)d_in[6];
    const float* b_dst  = (const float*)d_in[7];
    const float* attn   = (const float*)d_in[8];
    const float* W_skip = (const float*)d_in[9];
    const float* b_skip = (const float*)d_in[10];
    const float* gamma  = (const float*)d_in[11];
    const float* beta   = (const float*)d_in[12];
    const float* W_red  = (const float*)d_in[13];
    const float* b_red  = (const float*)d_in[14];
    const float* w_gate = (const float*)d_in[15];
    const float* W1     = (const float*)d_in[17];
    const float* b1     = (const float*)d_in[18];
    const float* W2     = (const float*)d_in[19];
    const float* b2     = (const float*)d_in[20];
    float* out = (float*)d_out;

    char* p = (char*)d_ws;
    auto alloc = [&](size_t bytes) -> char* {
        char* r = p;
        p += (bytes + 255) & ~(size_t)255;
        return r;
    };
    u16*   FS16     = (u16*)alloc((size_t)N_NODES * F2 * 2);
    u16*   FD16     = (u16*)alloc((size_t)N_NODES * F2 * 2);
    u16*   h1hi     = (u16*)alloc((size_t)N_NODES * F2 * 2);
    u16*   h1lo     = (u16*)alloc((size_t)N_NODES * F2 * 2);
    float* gate     = (float*)alloc((size_t)N_NODES * 4);
    float* stats    = (float*)alloc(1024 * 4);
    float* bias2    = (float*)alloc(256 * 4);
    float* h_gnum   = (float*)alloc((size_t)N_GRAPH * HID * 4);
    float* gden     = (float*)alloc((size_t)N_GRAPH * 4);
    int* counts     = (int*)alloc((size_t)N_NODES * 4);
    int* row_ptr    = (int*)alloc((size_t)(N_NODES + 1) * 4);
    int* cursor     = (int*)alloc((size_t)N_NODES * 4);
    int* csr_src    = (int*)alloc((size_t)N_EDGES * 4);
    int* bsum       = (int*)alloc((size_t)SCAN_BLOCKS * 4);
    u16* Fhi        = (u16*)alloc((size_t)RT_PAD * IN_DIM * 2);  // padded; aliased as hr later
    u16* Wthi       = (u16*)alloc((size_t)4 * 512 * 512 * 2);
    u16* Wtlo       = (u16*)alloc((size_t)4 * 512 * 512 * 2);
    u16* Wphi       = (u16*)alloc((size_t)HID * 512 * 2);  // BN-folded reducer weights
    u16* Wplo       = (u16*)alloc((size_t)HID * 512 * 2);
    // hr (20.48 MB) aliases Fhi (20.58 MB): Fhi's last use (input GEMMs)
    // strictly precedes hr's first write (reducer GEMM).
    float* hr = (float*)Fhi;
    (void)ws_size; (void)in_sizes; (void)n_in; (void)out_size;

    const size_t WSZ = (size_t)512 * 512;

    // 1. prep: feat->bf16 + weight transpose/split + zero-init (fused)
    prep_kernel<<<PREP_BLOCKS, 256, 0, stream>>>(
        feat, Fhi, W_src, W_dst, W_skip, W_red, Wthi, Wtlo,
        counts, cursor, stats, h_gnum, gden, gate);

    // 2. fused input GEMM triple (transposed-C epilogue) + hist rides along
    gemm_mfma_triple<<<TRIPLE_BLOCKS + HIST_BLOCKS, 256, 0, stream>>>(
        Fhi, Wthi, b_src, b_dst, b_skip, FS16, FD16, h1hi, h1lo, dst, counts);

    // 3-5. CSR scan + scatter
    scan_local_kernel<<<SCAN_BLOCKS, 256, 0, stream>>>(counts, row_ptr, bsum);
    scan_fixup_kernel<<<SCAN_BLOCKS, 256, 0, stream>>>(bsum, row_ptr);
    scatter_kernel<<<(N_EDGES + 255) / 256, 256, 0, stream>>>(src, dst, row_ptr, cursor, csr_src);

    // 6. fused edge phase (single pass; ELU+skip RMW on h1 hi/lo)
    edge_fused_kernel<<<N_NODES, 256, 0, stream>>>(
        FS16, FD16, attn, csr_src, row_ptr, h1hi, h1lo);

    // 7-8. BN stats -> finalize+fold into reducer weights (one kernel)
    bn_stats_kernel<<<500, 256, 0, stream>>>(h1hi, stats, 40);
    bn_fold_kernel<<<HID, 256, 0, stream>>>(
        stats, gamma, beta, Wthi + 3 * WSZ, Wtlo + 3 * WSZ, b_red, Wphi, Wplo, bias2);

    // 9. hr = h1 @ W' + bias'  (3-term MFMA; gate fused; float4 stores)
    dim3 g256((N_NODES + 127) / 128, 2);
    gemm_mfma_red<<<g256, 256, 0, stream>>>(
        h1hi, h1lo, Wphi, Wplo, bias2, w_gate, hr, gate);

    // 10. per-graph pooling (8 partial blocks per graph)
    pool_partial_kernel<<<N_GRAPH * 8, 256, 0, stream>>>(hr, gate, gids, h_gnum, gden);

    // 11. classifier (+ pooling divide)
    classifier_kernel<<<N_GRAPH, 128, 0, stream>>>(h_gnum, gden, W1, b1, W2, b2, out);
}